// Round 2
// baseline (1222.683 us; speedup 1.0000x reference)
//
#include <hip/hip_runtime.h>
#include <cstdint>

// MatrixReLU via matrix-sign Newton-Schulz:
//   out = 0.5*(X + eps*I + |B|),  B = X - eps*I,  |B| = B*sign(B)
// sign(B): 4 quintic (Muon coeffs) + 3 cubic NS iterations on scaled B.
// One block per 64x64 matrix; 256 threads; 4x4 tile per thread; fp32 vector ALU.

#define EPSV 1e-4f
#define LDSTR 68   // row stride in floats: 16B-aligned float4s, <=2-way bank conflict

__device__ __forceinline__ float blockReduceSum(float v, float* red) {
  #pragma unroll
  for (int o = 32; o >= 1; o >>= 1) v += __shfl_xor(v, o, 64);
  const int t = threadIdx.x;
  __syncthreads();                 // protect red[] from previous use
  if ((t & 63) == 0) red[t >> 6] = v;
  __syncthreads();
  return red[0] + red[1] + red[2] + red[3];
}

// acc = P * Q  (both 64x64 in LDS with row stride LDSTR), 4x4 tile at (r0,c0)
__device__ __forceinline__ void mm64(const float* __restrict__ P,
                                     const float* __restrict__ Q,
                                     float acc[4][4], int r0, int c0) {
  #pragma unroll
  for (int i = 0; i < 4; i++)
    #pragma unroll
    for (int j = 0; j < 4; j++) acc[i][j] = 0.f;

  #pragma unroll 2
  for (int k = 0; k < 64; k += 4) {
    float4 a0 = *reinterpret_cast<const float4*>(&P[(r0 + 0) * LDSTR + k]);
    float4 a1 = *reinterpret_cast<const float4*>(&P[(r0 + 1) * LDSTR + k]);
    float4 a2 = *reinterpret_cast<const float4*>(&P[(r0 + 2) * LDSTR + k]);
    float4 a3 = *reinterpret_cast<const float4*>(&P[(r0 + 3) * LDSTR + k]);
    float4 b0 = *reinterpret_cast<const float4*>(&Q[(k + 0) * LDSTR + c0]);
    float4 b1 = *reinterpret_cast<const float4*>(&Q[(k + 1) * LDSTR + c0]);
    float4 b2 = *reinterpret_cast<const float4*>(&Q[(k + 2) * LDSTR + c0]);
    float4 b3 = *reinterpret_cast<const float4*>(&Q[(k + 3) * LDSTR + c0]);
#define ROWUP(i, ai)                                                          \
    acc[i][0] += ai.x * b0.x + ai.y * b1.x + ai.z * b2.x + ai.w * b3.x;       \
    acc[i][1] += ai.x * b0.y + ai.y * b1.y + ai.z * b2.y + ai.w * b3.y;       \
    acc[i][2] += ai.x * b0.z + ai.y * b1.z + ai.z * b2.z + ai.w * b3.z;       \
    acc[i][3] += ai.x * b0.w + ai.y * b1.w + ai.z * b2.w + ai.w * b3.w;
    ROWUP(0, a0) ROWUP(1, a1) ROWUP(2, a2) ROWUP(3, a3)
#undef ROWUP
  }
}

__device__ __forceinline__ void readOwn(const float* B, float o[4][4], int r0, int c0) {
  #pragma unroll
  for (int i = 0; i < 4; i++) {
    float4 v = *reinterpret_cast<const float4*>(&B[(r0 + i) * LDSTR + c0]);
    o[i][0] = v.x; o[i][1] = v.y; o[i][2] = v.z; o[i][3] = v.w;
  }
}

__device__ __forceinline__ void writeOwn(float* B, const float o[4][4], int r0, int c0) {
  #pragma unroll
  for (int i = 0; i < 4; i++) {
    float4 v = make_float4(o[i][0], o[i][1], o[i][2], o[i][3]);
    *reinterpret_cast<float4*>(&B[(r0 + i) * LDSTR + c0]) = v;
  }
}

__global__ __launch_bounds__(256, 3) void mrelu_kernel(const float* __restrict__ X,
                                                       float* __restrict__ O) {
  __shared__ float Ybuf[64 * LDSTR];
  __shared__ float Zbuf[64 * LDSTR];
  __shared__ float Wbuf[64 * LDSTR];
  __shared__ float red[4];

  const int t = threadIdx.x;
  const int r0 = (t >> 4) * 4;
  const int c0 = (t & 15) * 4;
  const size_t base = (size_t)blockIdx.x * 4096;
  const float* Xb = X + base;

  // ---- load X, form B = X - eps*I, accumulate ||B||_F^2 ----
  float4 ld[4];
  float ssq = 0.f;
  #pragma unroll
  for (int q = 0; q < 4; q++) {
    float4 v = reinterpret_cast<const float4*>(Xb)[t + 256 * q];
    const int e = 4 * t + 1024 * q;
    const int row = e >> 6, col = e & 63;
    const int d = row - col;
    if (d >= 0 && d < 4) (&v.x)[d] -= EPSV;
    ssq += v.x * v.x + v.y * v.y + v.z * v.z + v.w * v.w;
    ld[q] = v;
  }
  const float s0sq = blockReduceSum(ssq, red);
  const float S0 = sqrtf(s0sq) + 1e-30f;
  const float invS0 = 1.0f / S0;
  #pragma unroll
  for (int q = 0; q < 4; q++) {
    const int e = 4 * t + 1024 * q;
    const int row = e >> 6, col = e & 63;
    float4 v = ld[q];
    v.x *= invS0; v.y *= invS0; v.z *= invS0; v.w *= invS0;
    *reinterpret_cast<float4*>(&Ybuf[row * LDSTR + col]) = v;
  }
  __syncthreads();

  // ---- Z = Y^2; tighten scale with r = ||Z||_F^(1/2) >= mu_max ----
  float zacc[4][4];
  mm64(Ybuf, Ybuf, zacc, r0, c0);
  float zss = 0.f;
  #pragma unroll
  for (int i = 0; i < 4; i++)
    #pragma unroll
    for (int j = 0; j < 4; j++) zss += zacc[i][j] * zacc[i][j];
  const float znSq = blockReduceSum(zss, red);           // = ||Z||_F^2
  const float rr = sqrtf(sqrtf(znSq + 1e-30f));          // = ||Z||_F^(1/2)
  const float invr = 1.0f / rr;
  const float invr2 = invr * invr;
  const float S = S0 * rr;                               // |lambda(B)| <= S

  float yown[4][4];
  readOwn(Ybuf, yown, r0, c0);
  __syncthreads();                                       // all reads of Y done
  #pragma unroll
  for (int i = 0; i < 4; i++)
    #pragma unroll
    for (int j = 0; j < 4; j++) { yown[i][j] *= invr; zacc[i][j] *= invr2; }
  writeOwn(Ybuf, yown, r0, c0);
  writeOwn(Wbuf, yown, r0, c0);                          // keep W = B/S for final |B| = S*(W*Y)
  writeOwn(Zbuf, zacc, r0, c0);
  __syncthreads();

  // ---- 4 quintic steps: Y <- a*Y + b*Y^3 + c*Y^5 ----
  const float qa = 3.4445f, qb = -4.7750f, qc = 2.0315f;
  #pragma unroll 1
  for (int it = 0; it < 4; it++) {
    float tacc[4][4];
    mm64(Zbuf, Ybuf, tacc, r0, c0);                      // T = Y^3
    readOwn(Ybuf, yown, r0, c0);
    __syncthreads();
    writeOwn(Ybuf, tacc, r0, c0);                        // Ybuf := T
    __syncthreads();
    float macc[4][4];
    mm64(Zbuf, Ybuf, macc, r0, c0);                      // M = Y^5
    __syncthreads();
    #pragma unroll
    for (int i = 0; i < 4; i++)
      #pragma unroll
      for (int j = 0; j < 4; j++)
        tacc[i][j] = qa * yown[i][j] + qb * tacc[i][j] + qc * macc[i][j];
    writeOwn(Ybuf, tacc, r0, c0);
    __syncthreads();
    mm64(Ybuf, Ybuf, zacc, r0, c0);                      // refresh Z = Y^2
    __syncthreads();
    writeOwn(Zbuf, zacc, r0, c0);
    __syncthreads();
  }

  // ---- 3 cubic NS steps: Y <- 1.5*Y - 0.5*Y^3 ----
  #pragma unroll 1
  for (int it = 0; it < 3; it++) {
    float macc[4][4];
    mm64(Zbuf, Ybuf, macc, r0, c0);                      // Y^3
    readOwn(Ybuf, yown, r0, c0);
    __syncthreads();
    #pragma unroll
    for (int i = 0; i < 4; i++)
      #pragma unroll
      for (int j = 0; j < 4; j++)
        macc[i][j] = 1.5f * yown[i][j] - 0.5f * macc[i][j];
    writeOwn(Ybuf, macc, r0, c0);
    __syncthreads();
    if (it < 2) {
      mm64(Ybuf, Ybuf, zacc, r0, c0);
      __syncthreads();
      writeOwn(Zbuf, zacc, r0, c0);
      __syncthreads();
    }
  }

  // ---- out = 0.5*S*(W + W*Y) + eps*I ----
  float pacc[4][4];
  mm64(Wbuf, Ybuf, pacc, r0, c0);
  readOwn(Wbuf, yown, r0, c0);
  float* Ob = O + base;
  const float hS = 0.5f * S;
  #pragma unroll
  for (int i = 0; i < 4; i++) {
    const int row = r0 + i;
    float4 v;
    v.x = hS * (yown[i][0] + pacc[i][0]) + ((row == c0 + 0) ? EPSV : 0.f);
    v.y = hS * (yown[i][1] + pacc[i][1]) + ((row == c0 + 1) ? EPSV : 0.f);
    v.z = hS * (yown[i][2] + pacc[i][2]) + ((row == c0 + 2) ? EPSV : 0.f);
    v.w = hS * (yown[i][3] + pacc[i][3]) + ((row == c0 + 3) ? EPSV : 0.f);
    *reinterpret_cast<float4*>(&Ob[row * 64 + c0]) = v;
  }
}

extern "C" void kernel_launch(void* const* d_in, const int* in_sizes, int n_in,
                              void* d_out, int out_size, void* d_ws, size_t ws_size,
                              hipStream_t stream) {
  const float* X = (const float*)d_in[0];
  float* O = (float*)d_out;
  const int nmat = in_sizes[0] >> 12;  // /4096
  mrelu_kernel<<<nmat, 256, 0, stream>>>(X, O);
}

// Round 5
// 517.688 us; speedup vs baseline: 2.3618x; 2.3618x over previous
//
#include <hip/hip_runtime.h>
#include <cstdint>

// MatrixReLU via matrix-sign Newton-Schulz on MFMA (bf16 2-term split products).
//   out = 0.5*(B + |B|) + eps*I,  B = X - eps*I,  |B| = B*sign(B)
// sign: 4 quintic (3.4445,-4.7750,2.0315) + 3 cubic NS steps.
// Every operand is symmetric -> B-fragments read row-wise from the same
// row-major LDS image as A-fragments; results written transposed (=same).
// 1 matrix/block, 256 threads (4 waves x 2x2 16x16 tiles), 64KB LDS, 2 blk/CU.

#define EPSV 1e-4f

typedef short bf16x8  __attribute__((ext_vector_type(8)));
typedef short short4v __attribute__((ext_vector_type(4)));
typedef float f32x4   __attribute__((ext_vector_type(4)));

__device__ __forceinline__ short f2bf(float f) {            // RNE fp32->bf16
  unsigned u = __float_as_uint(f);
  return (short)((u + 0x7FFFu + ((u >> 16) & 1u)) >> 16);
}
__device__ __forceinline__ float bf2f(short s) {
  return __uint_as_float(((unsigned)(unsigned short)s) << 16);
}
// XOR swizzle: spreads 8 consecutive 128B rows across 8 16B slots (G4 fix)
__device__ __forceinline__ int swz(int row, int byte) { return byte ^ ((row & 7) << 4); }

// 8 contiguous bf16 of row `row` at byte offset kb (A-frag; B-frag by symmetry)
__device__ __forceinline__ bf16x8 ldfrag(const short* S, int row, int kb) {
  return *(const bf16x8*)((const char*)S + swz(row, row * 128 + kb));
}

__device__ __forceinline__ float blockReduceSum(float v, float* red) {
  #pragma unroll
  for (int o = 32; o >= 1; o >>= 1) v += __shfl_xor(v, o, 64);
  const int t = threadIdx.x;
  __syncthreads();
  if ((t & 63) == 0) red[t >> 6] = v;
  __syncthreads();
  return red[0] + red[1] + red[2] + red[3];
}

// acc = P*Q with split operands: Ph*Qh + Ph*Ql + Pl*Qh, fp32 accumulate.
__device__ __forceinline__ void mm_split(const short* Ph, const short* Pl,
                                         const short* Qh, const short* Ql,
                                         int Rb, int Cb, int l15, int kg,
                                         f32x4 acc[2][2]) {
  #pragma unroll
  for (int mi = 0; mi < 2; mi++)
    #pragma unroll
    for (int ni = 0; ni < 2; ni++) acc[mi][ni] = (f32x4){0.f, 0.f, 0.f, 0.f};
  #pragma unroll
  for (int ks = 0; ks < 2; ks++) {
    const int kb = 64 * ks + 16 * kg;   // k = 32*ks + 8*kg + [0..7]
    bf16x8 ah0 = ldfrag(Ph, Rb + l15,      kb);
    bf16x8 ah1 = ldfrag(Ph, Rb + 16 + l15, kb);
    bf16x8 al0 = ldfrag(Pl, Rb + l15,      kb);
    bf16x8 al1 = ldfrag(Pl, Rb + 16 + l15, kb);
    bf16x8 bh0 = ldfrag(Qh, Cb + l15,      kb);   // B[k][c]=Q[c][k] (symmetric)
    bf16x8 bh1 = ldfrag(Qh, Cb + 16 + l15, kb);
    bf16x8 bl0 = ldfrag(Ql, Cb + l15,      kb);
    bf16x8 bl1 = ldfrag(Ql, Cb + 16 + l15, kb);
#define MM(mi, ni, A, B) acc[mi][ni] = __builtin_amdgcn_mfma_f32_16x16x32_bf16(A, B, acc[mi][ni], 0, 0, 0)
    MM(0,0,ah0,bh0); MM(0,0,ah0,bl0); MM(0,0,al0,bh0);
    MM(0,1,ah0,bh1); MM(0,1,ah0,bl1); MM(0,1,al0,bh1);
    MM(1,0,ah1,bh0); MM(1,0,ah1,bl0); MM(1,0,al1,bh0);
    MM(1,1,ah1,bh1); MM(1,1,ah1,bl1); MM(1,1,al1,bh1);
#undef MM
  }
}

// write vals (tile (mi,ni), C-layout) transposed into Dh/Dl as h/l bf16 split.
// Transposed positions == true positions since result is symmetric.
__device__ __forceinline__ void writeSym(short* Dh, short* Dl, const f32x4 vals[2][2],
                                         int Rb, int Cb, int l15, int kg, float scale) {
  #pragma unroll
  for (int mi = 0; mi < 2; mi++)
    #pragma unroll
    for (int ni = 0; ni < 2; ni++) {
      const int rp = Cb + 16 * ni + l15;          // transposed row  = C col
      const int cb2 = (Rb + 16 * mi + 4 * kg) * 2; // transposed col base (bytes)
      short4v h, l;
      #pragma unroll
      for (int r = 0; r < 4; r++) {
        float v = vals[mi][ni][r] * scale;
        short hh = f2bf(v);
        h[r] = hh;
        l[r] = f2bf(v - bf2f(hh));
      }
      const int off = swz(rp, rp * 128 + cb2);
      *(short4v*)((char*)Dh + off) = h;
      *(short4v*)((char*)Dl + off) = l;
    }
}

// read this lane's own (transposed-tile) positions, reconstruct fp32 = h + l
__device__ __forceinline__ void readSym(const short* Sh, const short* Sl,
                                        int Rb, int Cb, int l15, int kg,
                                        f32x4 out[2][2]) {
  #pragma unroll
  for (int mi = 0; mi < 2; mi++)
    #pragma unroll
    for (int ni = 0; ni < 2; ni++) {
      const int rp = Cb + 16 * ni + l15;
      const int off = swz(rp, rp * 128 + (Rb + 16 * mi + 4 * kg) * 2);
      short4v h = *(const short4v*)((const char*)Sh + off);
      short4v l = *(const short4v*)((const char*)Sl + off);
      #pragma unroll
      for (int r = 0; r < 4; r++) out[mi][ni][r] = bf2f(h[r]) + bf2f(l[r]);
    }
}

__global__ __launch_bounds__(256, 2) void mrelu_mfma(const float* __restrict__ X,
                                                     float* __restrict__ O) {
  __shared__ short Yh[4096], Yl[4096], Zh[4096], Zl[4096],
                   Uh[4096], Ul[4096], Wh[4096], Wl[4096];
  __shared__ float red[4];

  const int t = threadIdx.x;
  const int lane = t & 63, wid = t >> 6;
  const int l15 = lane & 15, kg = lane >> 4;
  const int Rb = (wid >> 1) * 32, Cb = (wid & 1) * 32;
  const size_t base = (size_t)blockIdx.x * 4096;
  const float* Xb = X + base;

  // ---- load X, B = X - eps*I, ||B||_F^2 ----
  float4 ld[4];
  float ssq = 0.f;
  #pragma unroll
  for (int q = 0; q < 4; q++) {
    float4 v = reinterpret_cast<const float4*>(Xb)[t + 256 * q];
    const int e = 4 * t + 1024 * q;
    const int row = e >> 6, col = e & 63;
    const int d = row - col;
    if (d >= 0 && d < 4) (&v.x)[d] -= EPSV;
    ssq += v.x * v.x + v.y * v.y + v.z * v.z + v.w * v.w;
    ld[q] = v;
  }
  const float s0sq = blockReduceSum(ssq, red);
  const float S0 = sqrtf(s0sq) + 1e-30f;
  const float invS0 = 1.0f / S0;

  // ---- write Y0 = B/S0 as bf16 h/l split ----
  #pragma unroll
  for (int q = 0; q < 4; q++) {
    const int e = 4 * t + 1024 * q;
    const int row = e >> 6, col = e & 63;
    short4v h, l;
    #pragma unroll
    for (int i = 0; i < 4; i++) {
      float v = (&ld[q].x)[i] * invS0;
      short hh = f2bf(v);
      h[i] = hh;
      l[i] = f2bf(v - bf2f(hh));
    }
    const int off = swz(row, row * 128 + col * 2);
    *(short4v*)((char*)Yh + off) = h;
    *(short4v*)((char*)Yl + off) = l;
  }
  __syncthreads();

  // ---- Z0 = Y0^2; tighten scale r = ||Z0||_F^(1/2) >= mu_max ----
  f32x4 acc[2][2];
  mm_split(Yh, Yl, Yh, Yl, Rb, Cb, l15, kg, acc);
  float zss = 0.f;
  #pragma unroll
  for (int mi = 0; mi < 2; mi++)
    #pragma unroll
    for (int ni = 0; ni < 2; ni++)
      #pragma unroll
      for (int r = 0; r < 4; r++) zss += acc[mi][ni][r] * acc[mi][ni][r];
  const float znSq = blockReduceSum(zss, red);
  const float rr = sqrtf(sqrtf(znSq + 1e-30f));
  const float invr = 1.0f / rr;
  const float S = S0 * rr;
  writeSym(Zh, Zl, acc, Rb, Cb, l15, kg, invr * invr);   // Z = Z0/r^2

  // ---- rescale Y by 1/r; copy into W ----
  {
    f32x4 yv[2][2];
    readSym(Yh, Yl, Rb, Cb, l15, kg, yv);   // all Y reads for Z0 already fenced
    #pragma unroll
    for (int mi = 0; mi < 2; mi++)
      #pragma unroll
      for (int ni = 0; ni < 2; ni++)
        #pragma unroll
        for (int r = 0; r < 4; r++) yv[mi][ni][r] *= invr;
    writeSym(Yh, Yl, yv, Rb, Cb, l15, kg, 1.0f);
    writeSym(Wh, Wl, yv, Rb, Cb, l15, kg, 1.0f);
  }
  __syncthreads();

  // ---- 4 quintic steps: Y <- qa*Y + qb*Y^3 + qc*Y^5 ----
  const float qa = 3.4445f, qb = -4.7750f, qc = 2.0315f;
  #pragma unroll 1
  for (int it = 0; it < 4; it++) {
    mm_split(Zh, Zl, Yh, Yl, Rb, Cb, l15, kg, acc);      // U = Z*Y = Y^3
    writeSym(Uh, Ul, acc, Rb, Cb, l15, kg, 1.0f);
    __syncthreads();
    mm_split(Zh, Zl, Uh, Ul, Rb, Cb, l15, kg, acc);      // M = Z*U = Y^5
    f32x4 yv[2][2], uv[2][2];
    readSym(Yh, Yl, Rb, Cb, l15, kg, yv);
    readSym(Uh, Ul, Rb, Cb, l15, kg, uv);
    f32x4 res[2][2];
    #pragma unroll
    for (int mi = 0; mi < 2; mi++)
      #pragma unroll
      for (int ni = 0; ni < 2; ni++)
        #pragma unroll
        for (int r = 0; r < 4; r++)
          res[mi][ni][r] = qa * yv[mi][ni][r] + qb * uv[mi][ni][r] + qc * acc[mi][ni][r];
    writeSym(Yh, Yl, res, Rb, Cb, l15, kg, 1.0f);        // own positions only
    __syncthreads();
    mm_split(Yh, Yl, Yh, Yl, Rb, Cb, l15, kg, acc);      // Z = Y^2
    writeSym(Zh, Zl, acc, Rb, Cb, l15, kg, 1.0f);
    __syncthreads();
  }

  // ---- 3 cubic NS steps: Y <- 1.5*Y - 0.5*Y^3 ----
  #pragma unroll 1
  for (int it = 0; it < 3; it++) {
    mm_split(Zh, Zl, Yh, Yl, Rb, Cb, l15, kg, acc);      // Y^3
    f32x4 yv[2][2];
    readSym(Yh, Yl, Rb, Cb, l15, kg, yv);
    __syncthreads();                                     // all Y reads done
    f32x4 res[2][2];
    #pragma unroll
    for (int mi = 0; mi < 2; mi++)
      #pragma unroll
      for (int ni = 0; ni < 2; ni++)
        #pragma unroll
        for (int r = 0; r < 4; r++)
          res[mi][ni][r] = 1.5f * yv[mi][ni][r] - 0.5f * acc[mi][ni][r];
    writeSym(Yh, Yl, res, Rb, Cb, l15, kg, 1.0f);
    __syncthreads();
    if (it < 2) {
      mm_split(Yh, Yl, Yh, Yl, Rb, Cb, l15, kg, acc);    // Z = Y^2
      writeSym(Zh, Zl, acc, Rb, Cb, l15, kg, 1.0f);
      __syncthreads();
    }
  }

  // ---- out = 0.5*S*(W + W*sign) + eps*I, transposed global store ----
  mm_split(Wh, Wl, Yh, Yl, Rb, Cb, l15, kg, acc);
  f32x4 wv[2][2];
  readSym(Wh, Wl, Rb, Cb, l15, kg, wv);
  float* Ob = O + base;
  const float hS = 0.5f * S;
  #pragma unroll
  for (int mi = 0; mi < 2; mi++)
    #pragma unroll
    for (int ni = 0; ni < 2; ni++) {
      const int rp = Cb + 16 * ni + l15;
      const int cb = Rb + 16 * mi + 4 * kg;
      float4 o;
      #pragma unroll
      for (int r = 0; r < 4; r++)
        (&o.x)[r] = hS * (wv[mi][ni][r] + acc[mi][ni][r]) + ((rp == cb + r) ? EPSV : 0.f);
      *reinterpret_cast<float4*>(&Ob[rp * 64 + cb]) = o;
    }
}

extern "C" void kernel_launch(void* const* d_in, const int* in_sizes, int n_in,
                              void* d_out, int out_size, void* d_ws, size_t ws_size,
                              hipStream_t stream) {
  const float* X = (const float*)d_in[0];
  float* O = (float*)d_out;
  const int nmat = in_sizes[0] >> 12;
  mrelu_mfma<<<nmat, 256, 0, stream>>>(X, O);
}